// Round 3
// baseline (87.699 us; speedup 1.0000x reference)
//
#include <hip/hip_runtime.h>

#define K 32
#define NB 8          // number of batches (values 0..NB-1)

// One-shot setup: pack src coords as float4{x,y,z,s2} (s2 with reference-exact
// fp32 rounding) and compute batch bounds via binary search (threads 0..NB of
// block 0).
__global__ void setup_kernel(const float* __restrict__ src_xyz,
                             const int* __restrict__ batch_src, int n_src,
                             int* __restrict__ bounds,
                             float4* __restrict__ packed) {
    const int i = blockIdx.x * blockDim.x + threadIdx.x;
    if (i < n_src) {
        const float x = src_xyz[3 * i + 0];
        const float y = src_xyz[3 * i + 1];
        const float z = src_xyz[3 * i + 2];
        const float s2 = __fadd_rn(__fadd_rn(__fmul_rn(x, x), __fmul_rn(y, y)),
                                   __fmul_rn(z, z));
        packed[i] = make_float4(x, y, z, s2);
    }
    if (i <= NB) {
        int lo = 0, hi = n_src;
        while (lo < hi) {
            int mid = (lo + hi) >> 1;
            if (batch_src[mid] < i) lo = mid + 1; else hi = mid;
        }
        bounds[i] = lo;
    }
}

__global__ __launch_bounds__(256) void RadiusConnect_kernel(
    const float4* __restrict__ src_p,
    const float* __restrict__ dst_xyz, const int* __restrict__ batch_dst,
    const int* __restrict__ bounds,
    int n_dst, int* __restrict__ out)
{
    const int wave = (blockIdx.x * blockDim.x + threadIdx.x) >> 6;
    const int lane = threadIdx.x & 63;
    if (wave >= n_dst) return;
    const int d = wave;

    // dst point + |dst|^2, reference-exact fp32 rounding (no FMA contraction).
    const float xd = dst_xyz[3 * d + 0];
    const float yd = dst_xyz[3 * d + 1];
    const float zd = dst_xyz[3 * d + 2];
    const float d2 = __fadd_rn(__fadd_rn(__fmul_rn(xd, xd), __fmul_rn(yd, yd)),
                               __fmul_rn(zd, zd));
    const int b = batch_dst[d];
    const int start = bounds[b];
    const int end   = bounds[b + 1];

    const float rr = __fmul_rn(0.2f, 0.2f);
    int* __restrict__ out_src = out;
    int* __restrict__ out_dst = out + (size_t)n_dst * K;
    const long long base = (long long)d * K;
    const unsigned long long lt = (1ull << lane) - 1ull;

    int count = 0;
    if (start < end) {
        const int last = end - 1;
        float4 cur[4], nxt[4];
        // prologue: load tile 0
#pragma unroll
        for (int g = 0; g < 4; ++g) {
            const int j = start + g * 64 + lane;
            cur[g] = src_p[j < last ? j : last];
        }
        int j0 = start;
        while (true) {
            const int jn = j0 + 256;
            const bool more = (jn < end);
            // prefetch tile i+1 BEFORE consuming tile i — breaks the serial
            // load-latency chain of the early-exit loop.
            if (more) {
#pragma unroll
                for (int g = 0; g < 4; ++g) {
                    const int j = jn + g * 64 + lane;
                    nxt[g] = src_p[j < last ? j : last];
                }
            }
            // compute + rank assignment on tile i
#pragma unroll
            for (int g = 0; g < 4; ++g) {
                const int j = j0 + g * 64 + lane;
                const float xs = cur[g].x, ys = cur[g].y, zs = cur[g].z;
                const float s2 = cur[g].w;
                const float cross = __fadd_rn(
                    __fadd_rn(__fmul_rn(xd, xs), __fmul_rn(yd, ys)),
                    __fmul_rn(zd, zs));
                const float dist2 = __fsub_rn(__fadd_rn(d2, s2),
                                              __fmul_rn(2.0f, cross));
                const bool valid = (j <= last) && (dist2 <= rr);
                const unsigned long long m = __ballot(valid);
                const int rank = count + __popcll(m & lt);
                if (valid && rank < K) {
                    out_src[base + rank] = j;
                    out_dst[base + rank] = d;
                }
                count += __popcll(m);
            }
            if (count >= K || !more) break;
            j0 = jn;
#pragma unroll
            for (int g = 0; g < 4; ++g) cur[g] = nxt[g];
        }
    }

    // Pad unfilled tail with -1 (d_out is re-poisoned before every call).
    if (count < K && lane >= count && lane < K) {
        out_src[base + lane] = -1;
        out_dst[base + lane] = -1;
    }
}

extern "C" void kernel_launch(void* const* d_in, const int* in_sizes, int n_in,
                              void* d_out, int out_size, void* d_ws, size_t ws_size,
                              hipStream_t stream) {
    const float* src_xyz   = (const float*)d_in[0];
    const int*   batch_src = (const int*)d_in[1];
    const float* dst_xyz   = (const float*)d_in[2];
    const int*   batch_dst = (const int*)d_in[3];
    int* out = (int*)d_out;

    int*    bounds = (int*)d_ws;                          // NB+1 ints
    float4* packed = (float4*)((char*)d_ws + 256);        // n_src float4s

    const int n_src = in_sizes[0] / 3;
    const int n_dst = in_sizes[2] / 3;

    setup_kernel<<<(n_src + 255) / 256, 256, 0, stream>>>(
        src_xyz, batch_src, n_src, bounds, packed);

    const int threads = 256;                               // 4 waves/block
    const int blocks = (n_dst * 64 + threads - 1) / threads;
    RadiusConnect_kernel<<<blocks, threads, 0, stream>>>(
        packed, dst_xyz, batch_dst, bounds, n_dst, out);
}